// Round 7
// baseline (318.800 us; speedup 1.0000x reference)
//
#include <hip/hip_runtime.h>
#include <stdint.h>

typedef short short8 __attribute__((ext_vector_type(8)));
typedef short short4v __attribute__((ext_vector_type(4)));
typedef float f32x4 __attribute__((ext_vector_type(4)));

#define LOG2E 1.44269504088896f
#define AS1 __attribute__((address_space(1)))
#define AS3 __attribute__((address_space(3)))

__device__ __forceinline__ float fexp2(float x) {
#if __has_builtin(__builtin_amdgcn_exp2f)
    return __builtin_amdgcn_exp2f(x);   // bare v_exp_f32 (flush-denorm ok: p<2^-126 ~ 0)
#else
    return exp2f(x);
#endif
}
__device__ __forceinline__ unsigned short f2bfbits(float f) {
    unsigned x = __builtin_bit_cast(unsigned, f);
    unsigned r = x + 0x7fffu + ((x >> 16) & 1u);
    return (unsigned short)(r >> 16);
}
__device__ __forceinline__ float bfbits2f(unsigned short b) {
    unsigned u = ((unsigned)b) << 16;
    return __builtin_bit_cast(float, u);
}
__device__ __forceinline__ void unpack8(uint4 u, float4& f0, float4& f1) {
    f0.x = bfbits2f((unsigned short)(u.x & 0xffffu)); f0.y = bfbits2f((unsigned short)(u.x >> 16));
    f0.z = bfbits2f((unsigned short)(u.y & 0xffffu)); f0.w = bfbits2f((unsigned short)(u.y >> 16));
    f1.x = bfbits2f((unsigned short)(u.z & 0xffffu)); f1.y = bfbits2f((unsigned short)(u.z >> 16));
    f1.z = bfbits2f((unsigned short)(u.w & 0xffffu)); f1.w = bfbits2f((unsigned short)(u.w >> 16));
}
__device__ __forceinline__ unsigned pack2(float a, float b) {
    return (unsigned)f2bfbits(a) | ((unsigned)f2bfbits(b) << 16);
}
// truncating pack (matches P truncation semantics)
__device__ __forceinline__ unsigned pack2t(float a, float b) {
    unsigned ba = __builtin_bit_cast(unsigned, a);
    unsigned bb = __builtin_bit_cast(unsigned, b);
    return (ba >> 16) | (bb & 0xffff0000u);
}
// K=16 bf16 MFMA: A[m=lm][k=quad*4+r], B[k=quad*4+r][n=lm], D[m=quad*4+r][n=lm]
__device__ __forceinline__ f32x4 mfma16(short4v a, short4v b, f32x4 c) {
#if __has_builtin(__builtin_amdgcn_mfma_f32_16x16x16bf16_1k)
    return __builtin_amdgcn_mfma_f32_16x16x16bf16_1k(a, b, c, 0, 0, 0);
#else
    asm("v_mfma_f32_16x16x16_bf16 %0, %1, %2, %0" : "+v"(c) : "v"(a), "v"(b));
    return c;
#endif
}
// async 16B/lane global->LDS; lp must be wave-uniform base, lanes scatter +lane*16
__device__ __forceinline__ void glds16(const void* gp, void* lp) {
    __builtin_amdgcn_global_load_lds((const AS1 unsigned*)(uintptr_t)gp,
                                     (AS3 unsigned*)(unsigned)(uintptr_t)lp, 16, 0, 0);
}

// ------- transpose + fp32->bf16 convert: src[R][C] fp32 -> dst[C][R] bf16 -------
__global__ __launch_bounds__(256) void t32cvt_k(const float* __restrict__ src,
                                                unsigned short* __restrict__ dst,
                                                int R, int C) {
    __shared__ float tile[32][36];
    int t = threadIdx.x;
    int bx = blockIdx.x, by = blockIdx.y;
    int r = t >> 3, c0 = (t & 7) * 4;
    *(float4*)&tile[r][c0] = *(const float4*)(src + (size_t)(by * 32 + r) * C + bx * 32 + c0);
    __syncthreads();
    uint2 u;
    u.x = pack2(tile[c0 + 0][r], tile[c0 + 1][r]);
    u.y = pack2(tile[c0 + 2][r], tile[c0 + 3][r]);
    *(uint2*)(dst + (size_t)(bx * 32 + r) * R + by * 32 + c0) = u;
}

// ---- GEMM (m97-style): C[M,N] = A[M,K] * Bt[N,K]^T bf16 ; C fp32 or bf16 ----
// AF32: A is fp32 in global; convert to bf16 (RNE pack2) during reg-staged A-write
// (replaces the separate xbf_k pass; numerics identical). B stays global_load_lds.
// T1 XCD swizzle: consecutive tiles land on the same XCD's L2 (grid % 8 == 0 here).
template <bool CF32, bool AF32>
__global__ __launch_bounds__(256) void gemm_k(const void* __restrict__ Av,
                                              const unsigned short* __restrict__ Bt,
                                              void* __restrict__ Cv,
                                              int M, int N, int K) {
    __shared__ unsigned short sA[128 * 32];   // [row][32] unpadded (16B/lane linear)
    __shared__ unsigned short sB[128 * 32];
    const unsigned short* A = (const unsigned short*)Av;
    const float* Af = (const float*)Av;
    int t = threadIdx.x;
    int wid = t >> 6, lane = t & 63;
    int wm = (wid >> 1) * 64, wn = (wid & 1) * 64;
    int lm = lane & 15, lq = lane >> 4;
    int nwg = gridDim.x * gridDim.y;
    int orig = blockIdx.y * gridDim.x + blockIdx.x;
    int swz = (orig & 7) * (nwg >> 3) + (orig >> 3);
    int bxi = swz % gridDim.x, byi = swz / gridDim.x;
    size_t m0 = (size_t)byi * 128, n0 = (size_t)bxi * 128;
    int srow = t >> 2, scol = (t & 3) * 8;
    const unsigned short* gb0 = Bt + (n0 + srow) * K + scol;
    const unsigned short* gb1 = Bt + (n0 + 64 + srow) * K + scol;
    unsigned short* laB0 = &sB[wid * 512];
    unsigned short* laB1 = &sB[2048 + wid * 512];
    // A staging (bf16 path): glds, wave-uniform base + lane*16 == srow*32+scol
    const unsigned short* ga0 = nullptr;
    const unsigned short* ga1 = nullptr;
    const float* fa0p = nullptr;
    const float* fa1p = nullptr;
    if constexpr (AF32) {
        fa0p = Af + (m0 + srow) * K + scol;
        fa1p = Af + (m0 + 64 + srow) * K + scol;
    } else {
        ga0 = A + (m0 + srow) * K + scol;
        ga1 = A + (m0 + 64 + srow) * K + scol;
    }
    unsigned short* laA0 = &sA[wid * 512];
    unsigned short* laA1 = &sA[2048 + wid * 512];
    f32x4 acc[4][4] = {};
    for (int k0 = 0; k0 < K; k0 += 32) {
        __syncthreads();
        if constexpr (AF32) {
            float4 a0 = *(const float4*)(fa0p + k0);
            float4 a1 = *(const float4*)(fa0p + k0 + 4);
            float4 b0 = *(const float4*)(fa1p + k0);
            float4 b1 = *(const float4*)(fa1p + k0 + 4);
            uint4 w0, w1;
            w0.x = pack2(a0.x, a0.y); w0.y = pack2(a0.z, a0.w);
            w0.z = pack2(a1.x, a1.y); w0.w = pack2(a1.z, a1.w);
            w1.x = pack2(b0.x, b0.y); w1.y = pack2(b0.z, b0.w);
            w1.z = pack2(b1.x, b1.y); w1.w = pack2(b1.z, b1.w);
            *(uint4*)&sA[srow * 32 + scol] = w0;
            *(uint4*)&sA[2048 + srow * 32 + scol] = w1;
        } else {
            glds16(ga0 + k0, laA0);
            glds16(ga1 + k0, laA1);
        }
        glds16(gb0 + k0, laB0);
        glds16(gb1 + k0, laB1);
        __syncthreads();
        short8 af[4], bfr[4];
        #pragma unroll
        for (int i = 0; i < 4; ++i) af[i] = *(const short8*)&sA[(wm + i * 16 + lm) * 32 + lq * 8];
        #pragma unroll
        for (int j = 0; j < 4; ++j) bfr[j] = *(const short8*)&sB[(wn + j * 16 + lm) * 32 + lq * 8];
        #pragma unroll
        for (int i = 0; i < 4; ++i)
            #pragma unroll
            for (int j = 0; j < 4; ++j)
                acc[i][j] = __builtin_amdgcn_mfma_f32_16x16x32_bf16(af[i], bfr[j], acc[i][j], 0, 0, 0);
    }
    #pragma unroll
    for (int i = 0; i < 4; ++i)
        #pragma unroll
        for (int j = 0; j < 4; ++j)
            #pragma unroll
            for (int r = 0; r < 4; ++r) {
                size_t row = m0 + wm + i * 16 + lq * 4 + r;
                size_t col = n0 + wn + j * 16 + lm;
                if (CF32) ((float*)Cv)[row * N + col] = acc[i][j][r];
                else ((unsigned short*)Cv)[row * N + col] = f2bfbits(acc[i][j][r]);
            }
}

// ------- V transpose: per (b,h): V[2048 k][64 d] -> Vt[64 d][2048 k], bf16 -------
__global__ __launch_bounds__(256) void vt_k(const unsigned short* __restrict__ qkv,
                                            unsigned short* __restrict__ vt) {
    __shared__ unsigned short tile[64 * 72];
    int kt = blockIdx.x, bh = blockIdx.y;
    int b = bh >> 4, h = bh & 15;
    const unsigned short* Vp = qkv + (size_t)b * 6291456 + 4194304 + (size_t)h * 131072;
    int t = threadIdx.x;
    int row = t >> 2, cc = (t & 3) * 16;
    const unsigned short* src = Vp + (size_t)(kt * 64 + row) * 64 + cc;
    *(uint4*)&tile[row * 72 + cc] = *(const uint4*)src;
    *(uint4*)&tile[row * 72 + cc + 8] = *(const uint4*)(src + 8);
    __syncthreads();
    unsigned v[8];
    #pragma unroll
    for (int j = 0; j < 8; ++j) {
        unsigned short a = tile[(cc + 2 * j) * 72 + row];
        unsigned short bsh = tile[(cc + 2 * j + 1) * 72 + row];
        v[j] = (unsigned)a | ((unsigned)bsh << 16);
    }
    unsigned short* dst = vt + ((size_t)bh * 64 + row) * 2048 + kt * 64 + cc;
    *(uint4*)dst = make_uint4(v[0], v[1], v[2], v[3]);
    *(uint4*)(dst + 8) = make_uint4(v[4], v[5], v[6], v[7]);
}

// ------- MFMA flash attention: block = (b,h, 128-q); 4 waves x 32 q -------
// (round-4 best-measured variant, 94.3 us) Reg-resident P (swapped QK^T -> x16 PV).
// Double-buffered K/V LDS in T14 order: prefetch EARLY (after barrier), ds_write
// LATE (after compute) into the other buffer -> 1 barrier/kt, no VGPR WAR window.
__global__ __launch_bounds__(256, 4) void attn_mfma(const unsigned short* __restrict__ qkv,
                                                    const unsigned short* __restrict__ vt,
                                                    unsigned short* __restrict__ aout) {
    __shared__ unsigned short Ks[2][64 * 72];  // [kk 64][d 64] pad 72
    __shared__ unsigned short Vs[2][64 * 72];  // [d 64][kk 64] pad 72
    int bid0 = blockIdx.x;
    int bid = (bid0 & 7) * 128 + (bid0 >> 3);  // XCD swizzle, nwg=1024 (%8==0 -> bijective)
    int qt = bid & 15, h = (bid >> 4) & 15, b = bid >> 8;
    int t = threadIdx.x;
    int wave = t >> 6, lane = t & 63, lm = lane & 15, quad = lane >> 4;
    const unsigned short* Qb = qkv + (size_t)b * 6291456 + (size_t)h * 131072;
    const unsigned short* Kb = Qb + 2097152;
    const unsigned short* Vtb = vt + (size_t)(b * 16 + h) * 131072;  // [64][2048]
    int q0 = qt * 128 + wave * 32;

    // persistent Q fragments, pre-scaled by 0.125 * log2(e) (folds softmax scale + exp2 base)
    const float qs = 0.125f * LOG2E;
    short8 qf[2][2];
    #pragma unroll
    for (int i = 0; i < 2; ++i)
        #pragma unroll
        for (int c = 0; c < 2; ++c) {
            uint4 u = *(const uint4*)(Qb + (size_t)(q0 + i * 16 + lm) * 64 + c * 32 + quad * 8);
            float4 f0, f1; unpack8(u, f0, f1);
            uint4 v;
            v.x = pack2(f0.x * qs, f0.y * qs);
            v.y = pack2(f0.z * qs, f0.w * qs);
            v.z = pack2(f1.x * qs, f1.y * qs);
            v.w = pack2(f1.z * qs, f1.w * qs);
            qf[i][c] = *(short8*)&v;
        }

    short4v ones4;
    #pragma unroll
    for (int z = 0; z < 4; ++z) ones4[z] = (short)0x3F80;  // bf16 1.0

    f32x4 o[2][4] = {};
    f32x4 l_acc[2] = {};

    int srow = t >> 2, scol = (t & 3) * 16;

    // prologue: load tile 0 and stage it into buf0
    uint4 k0r, k1r, v0r, v1r;
    {
        const unsigned short* kp = Kb + (size_t)srow * 64 + scol;
        k0r = *(const uint4*)kp;
        k1r = *(const uint4*)(kp + 8);
        const unsigned short* vp = Vtb + (size_t)srow * 2048 + scol;
        v0r = *(const uint4*)vp;
        v1r = *(const uint4*)(vp + 8);
        *(uint4*)&Ks[0][srow * 72 + scol] = k0r;
        *(uint4*)&Ks[0][srow * 72 + scol + 8] = k1r;
        *(uint4*)&Vs[0][srow * 72 + scol] = v0r;
        *(uint4*)&Vs[0][srow * 72 + scol + 8] = v1r;
    }

    #pragma unroll 1
    for (int kt = 0; kt < 32; ++kt) {
        __syncthreads();   // buf[kt&1] (staged at end of prev iter / prologue) visible

        // issue next tile's global loads now; they land during this tile's compute
        if (kt < 31) {
            const unsigned short* kp = Kb + (size_t)((kt + 1) * 64 + srow) * 64 + scol;
            k0r = *(const uint4*)kp;
            k1r = *(const uint4*)(kp + 8);
            const unsigned short* vp = Vtb + (size_t)srow * 2048 + (kt + 1) * 64 + scol;
            v0r = *(const uint4*)vp;
            v1r = *(const uint4*)(vp + 8);
        }

        const unsigned short* ks = Ks[kt & 1];
        const unsigned short* vs = Vs[kt & 1];
        __builtin_amdgcn_s_setprio(1);

        // S^T = K Q^T per 16x16 tile: mfma(kf, qf) -> D[row=k-local][col=q-local].
        // Lane (lm,quad) holds P[q=i*16+lm][k=j*16+quad*4+0..3] == A-fragment of the
        // K=16 MFMA -> exp2+pack to short4 in registers, feed PV directly.
        short4v pf[2][4];
        #pragma unroll
        for (int j = 0; j < 4; ++j) {
            short8 kf0 = *(const short8*)&ks[(j * 16 + lm) * 72 + quad * 8];
            short8 kf1 = *(const short8*)&ks[(j * 16 + lm) * 72 + 32 + quad * 8];
            #pragma unroll
            for (int i = 0; i < 2; ++i) {
                f32x4 sf = {0.f, 0.f, 0.f, 0.f};
                sf = __builtin_amdgcn_mfma_f32_16x16x32_bf16(kf0, qf[i][0], sf, 0, 0, 0);
                sf = __builtin_amdgcn_mfma_f32_16x16x32_bf16(kf1, qf[i][1], sf, 0, 0, 0);
                uint2 u;
                u.x = pack2t(fexp2(sf[0]), fexp2(sf[1]));
                u.y = pack2t(fexp2(sf[2]), fexp2(sf[3]));
                pf[i][j] = *(short4v*)&u;
            }
        }

        // O += P V (K=16 MFMA, P from regs; V fragment = ds_read_b64 from Vt layout)
        #pragma unroll
        for (int jd = 0; jd < 4; ++jd)
            #pragma unroll
            for (int j = 0; j < 4; ++j) {
                short4v vf = *(const short4v*)&vs[(jd * 16 + lm) * 72 + j * 16 + quad * 4];
                o[0][jd] = mfma16(pf[0][j], vf, o[0][jd]);
                o[1][jd] = mfma16(pf[1][j], vf, o[1][jd]);
            }
        // l += P * ones (row-sums on MFMA pipe, same D layout as o)
        #pragma unroll
        for (int j = 0; j < 4; ++j) {
            l_acc[0] = mfma16(pf[0][j], ones4, l_acc[0]);
            l_acc[1] = mfma16(pf[1][j], ones4, l_acc[1]);
        }
        __builtin_amdgcn_s_setprio(0);

        // write-late: stage tile kt+1 into the other buffer. Safe with 1 barrier/kt:
        // any wave's reads of buf[(kt+1)&1] (its compute at kt-1) completed before it
        // arrived at barrier(kt), which this wave has passed.
        if (kt < 31) {
            unsigned short* kd = Ks[(kt + 1) & 1];
            unsigned short* vd = Vs[(kt + 1) & 1];
            *(uint4*)&kd[srow * 72 + scol] = k0r;
            *(uint4*)&kd[srow * 72 + scol + 8] = k1r;
            *(uint4*)&vd[srow * 72 + scol] = v0r;
            *(uint4*)&vd[srow * 72 + scol + 8] = v1r;
        }
    }
    // epilogue: aout[b*2048 + q][h*64 + d] bf16
    #pragma unroll
    for (int i = 0; i < 2; ++i)
        #pragma unroll
        for (int r = 0; r < 4; ++r) {
            float inv = 1.f / l_acc[i][r];
            int q = q0 + i * 16 + quad * 4 + r;
            size_t rowbase = ((size_t)b * 2048 + q) * 1024 + h * 64;
            #pragma unroll
            for (int jd = 0; jd < 4; ++jd)
                aout[rowbase + jd * 16 + lm] = f2bfbits(o[i][jd][r] * inv);
        }
}

extern "C" void kernel_launch(void* const* d_in, const int* in_sizes, int n_in,
                              void* d_out, int out_size, void* d_ws, size_t ws_size,
                              hipStream_t stream) {
    const float* xin  = (const float*)d_in[0];   // [8192,1024] fp32
    const float* wqkv = (const float*)d_in[1];   // [1024,3072] fp32
    const float* wo   = (const float*)d_in[2];   // [1024,1024] fp32
    float* out = (float*)d_out;                  // [8192,1024] fp32

    char* ws = (char*)d_ws;
    unsigned short* qkv   = (unsigned short*)(ws);                 // 50,331,648 B
    unsigned short* attn  = (unsigned short*)(ws + 50331648);      // 16,777,216 B
    unsigned short* wqkvT = (unsigned short*)(ws + 67108864);      //  6,291,456 B
    unsigned short* woT   = (unsigned short*)(ws + 73400320);      //  2,097,152 B
    unsigned short* vt    = (unsigned short*)(ws + 75497472);      // 16,777,216 B

    dim3 blk(256);
    t32cvt_k<<<dim3(3072 / 32, 1024 / 32), blk, 0, stream>>>(wqkv, wqkvT, 1024, 3072);
    t32cvt_k<<<dim3(1024 / 32, 1024 / 32), blk, 0, stream>>>(wo, woT, 1024, 1024);
    gemm_k<false, true><<<dim3(3072 / 128, 8192 / 128), blk, 0, stream>>>(xin, wqkvT, qkv, 8192, 3072, 1024);
    vt_k<<<dim3(32, 64), blk, 0, stream>>>(qkv, vt);
    attn_mfma<<<dim3(1024), blk, 0, stream>>>(qkv, vt, attn);
    gemm_k<true, false><<<dim3(1024 / 128, 8192 / 128), blk, 0, stream>>>(attn, woT, out, 8192, 1024, 1024);
}

// Round 8
// 275.615 us; speedup vs baseline: 1.1567x; 1.1567x over previous
//
#include <hip/hip_runtime.h>
#include <stdint.h>

typedef short short8 __attribute__((ext_vector_type(8)));
typedef short short4v __attribute__((ext_vector_type(4)));
typedef float f32x4 __attribute__((ext_vector_type(4)));

#define LOG2E 1.44269504088896f
#define AS1 __attribute__((address_space(1)))
#define AS3 __attribute__((address_space(3)))

__device__ __forceinline__ float fexp2(float x) {
#if __has_builtin(__builtin_amdgcn_exp2f)
    return __builtin_amdgcn_exp2f(x);   // bare v_exp_f32 (flush-denorm ok: p<2^-126 ~ 0)
#else
    return exp2f(x);
#endif
}
__device__ __forceinline__ unsigned short f2bfbits(float f) {
    unsigned x = __builtin_bit_cast(unsigned, f);
    unsigned r = x + 0x7fffu + ((x >> 16) & 1u);
    return (unsigned short)(r >> 16);
}
__device__ __forceinline__ float bfbits2f(unsigned short b) {
    unsigned u = ((unsigned)b) << 16;
    return __builtin_bit_cast(float, u);
}
__device__ __forceinline__ void unpack8(uint4 u, float4& f0, float4& f1) {
    f0.x = bfbits2f((unsigned short)(u.x & 0xffffu)); f0.y = bfbits2f((unsigned short)(u.x >> 16));
    f0.z = bfbits2f((unsigned short)(u.y & 0xffffu)); f0.w = bfbits2f((unsigned short)(u.y >> 16));
    f1.x = bfbits2f((unsigned short)(u.z & 0xffffu)); f1.y = bfbits2f((unsigned short)(u.z >> 16));
    f1.z = bfbits2f((unsigned short)(u.w & 0xffffu)); f1.w = bfbits2f((unsigned short)(u.w >> 16));
}
__device__ __forceinline__ unsigned pack2(float a, float b) {
    return (unsigned)f2bfbits(a) | ((unsigned)f2bfbits(b) << 16);
}
// truncating pack (matches P truncation semantics)
__device__ __forceinline__ unsigned pack2t(float a, float b) {
    unsigned ba = __builtin_bit_cast(unsigned, a);
    unsigned bb = __builtin_bit_cast(unsigned, b);
    return (ba >> 16) | (bb & 0xffff0000u);
}
// K=16 bf16 MFMA: A[m=lm][k=quad*4+r], B[k=quad*4+r][n=lm], D[m=quad*4+r][n=lm]
__device__ __forceinline__ f32x4 mfma16(short4v a, short4v b, f32x4 c) {
#if __has_builtin(__builtin_amdgcn_mfma_f32_16x16x16bf16_1k)
    return __builtin_amdgcn_mfma_f32_16x16x16bf16_1k(a, b, c, 0, 0, 0);
#else
    asm("v_mfma_f32_16x16x16_bf16 %0, %1, %2, %0" : "+v"(c) : "v"(a), "v"(b));
    return c;
#endif
}
// async 16B/lane global->LDS; lp must be wave-uniform base, lanes scatter +lane*16
__device__ __forceinline__ void glds16(const void* gp, void* lp) {
    __builtin_amdgcn_global_load_lds((const AS1 unsigned*)(uintptr_t)gp,
                                     (AS3 unsigned*)(unsigned)(uintptr_t)lp, 16, 0, 0);
}

// ------- flat fp32 -> bf16 convert (RNE) -------
__global__ __launch_bounds__(256) void xbf_k(const float* __restrict__ x,
                                             unsigned short* __restrict__ y) {
    int i = (blockIdx.x * 256 + threadIdx.x) * 4;
    float4 v = *(const float4*)(x + i);
    uint2 u;
    u.x = pack2(v.x, v.y);
    u.y = pack2(v.z, v.w);
    *(uint2*)(y + i) = u;
}

// ------- transpose + fp32->bf16 convert: src[R][C] fp32 -> dst[C][R] bf16 -------
__global__ __launch_bounds__(256) void t32cvt_k(const float* __restrict__ src,
                                                unsigned short* __restrict__ dst,
                                                int R, int C) {
    __shared__ float tile[32][36];
    int t = threadIdx.x;
    int bx = blockIdx.x, by = blockIdx.y;
    int r = t >> 3, c0 = (t & 7) * 4;
    *(float4*)&tile[r][c0] = *(const float4*)(src + (size_t)(by * 32 + r) * C + bx * 32 + c0);
    __syncthreads();
    uint2 u;
    u.x = pack2(tile[c0 + 0][r], tile[c0 + 1][r]);
    u.y = pack2(tile[c0 + 2][r], tile[c0 + 3][r]);
    *(uint2*)(dst + (size_t)(bx * 32 + r) * R + by * 32 + c0) = u;
}

// ---- GEMM: C[M,N] = A[M,K] bf16 * Bt[N,K]^T bf16 ; C fp32 or bf16 ----
// T3 minimum 2-phase: single barrier per K-step, double-buffered LDS; the glds16
// loads for tile t+1 are issued before compute(t) and drained by the NEXT
// iteration's __syncthreads (which emits vmcnt(0) before s_barrier) -> load
// latency hides under the MFMA phase. T1 XCD swizzle (grids % 8 == 0 here).
template <bool CF32>
__global__ __launch_bounds__(256) void gemm_k(const unsigned short* __restrict__ A,
                                              const unsigned short* __restrict__ Bt,
                                              void* __restrict__ Cv,
                                              int M, int N, int K) {
    __shared__ unsigned short sA[2][128 * 32];   // [row][32] unpadded (glds16 linear)
    __shared__ unsigned short sB[2][128 * 32];
    int t = threadIdx.x;
    int wid = t >> 6, lane = t & 63;
    int wm = (wid >> 1) * 64, wn = (wid & 1) * 64;
    int lm = lane & 15, lq = lane >> 4;
    int nwg = gridDim.x * gridDim.y;
    int orig = blockIdx.y * gridDim.x + blockIdx.x;
    int swz = (orig & 7) * (nwg >> 3) + (orig >> 3);
    int bxi = swz % gridDim.x, byi = swz / gridDim.x;
    size_t m0 = (size_t)byi * 128, n0 = (size_t)bxi * 128;
    int srow = t >> 2, scol = (t & 3) * 8;
    const unsigned short* ga0 = A + (m0 + srow) * K + scol;
    const unsigned short* ga1 = A + (m0 + 64 + srow) * K + scol;
    const unsigned short* gb0 = Bt + (n0 + srow) * K + scol;
    const unsigned short* gb1 = Bt + (n0 + 64 + srow) * K + scol;
    int l0 = wid * 512, l1 = 2048 + wid * 512;

    // prologue: stage tile 0 into buf 0
    glds16(ga0, &sA[0][l0]);
    glds16(ga1, &sA[0][l1]);
    glds16(gb0, &sB[0][l0]);
    glds16(gb1, &sB[0][l1]);

    f32x4 acc[4][4] = {};
    int cur = 0;
    for (int k0 = 0; k0 < K; k0 += 32) {
        __syncthreads();   // per-wave vmcnt(0)+lgkmcnt(0) then s_barrier: buf[cur] ready,
                           // and all waves' reads of buf[cur^1] retired -> safe to restage.
        if (k0 + 32 < K) {
            glds16(ga0 + k0 + 32, &sA[cur ^ 1][l0]);
            glds16(ga1 + k0 + 32, &sA[cur ^ 1][l1]);
            glds16(gb0 + k0 + 32, &sB[cur ^ 1][l0]);
            glds16(gb1 + k0 + 32, &sB[cur ^ 1][l1]);
        }
        short8 af[4], bfr[4];
        #pragma unroll
        for (int i = 0; i < 4; ++i) af[i] = *(const short8*)&sA[cur][(wm + i * 16 + lm) * 32 + lq * 8];
        #pragma unroll
        for (int j = 0; j < 4; ++j) bfr[j] = *(const short8*)&sB[cur][(wn + j * 16 + lm) * 32 + lq * 8];
        __builtin_amdgcn_s_setprio(1);
        #pragma unroll
        for (int i = 0; i < 4; ++i)
            #pragma unroll
            for (int j = 0; j < 4; ++j)
                acc[i][j] = __builtin_amdgcn_mfma_f32_16x16x32_bf16(af[i], bfr[j], acc[i][j], 0, 0, 0);
        __builtin_amdgcn_s_setprio(0);
        cur ^= 1;
    }
    #pragma unroll
    for (int i = 0; i < 4; ++i)
        #pragma unroll
        for (int j = 0; j < 4; ++j)
            #pragma unroll
            for (int r = 0; r < 4; ++r) {
                size_t row = m0 + wm + i * 16 + lq * 4 + r;
                size_t col = n0 + wn + j * 16 + lm;
                if (CF32) ((float*)Cv)[row * N + col] = acc[i][j][r];
                else ((unsigned short*)Cv)[row * N + col] = f2bfbits(acc[i][j][r]);
            }
}

// ------- V transpose: per (b,h): V[2048 k][64 d] -> Vt[64 d][2048 k], bf16 -------
__global__ __launch_bounds__(256) void vt_k(const unsigned short* __restrict__ qkv,
                                            unsigned short* __restrict__ vt) {
    __shared__ unsigned short tile[64 * 72];
    int kt = blockIdx.x, bh = blockIdx.y;
    int b = bh >> 4, h = bh & 15;
    const unsigned short* Vp = qkv + (size_t)b * 6291456 + 4194304 + (size_t)h * 131072;
    int t = threadIdx.x;
    int row = t >> 2, cc = (t & 3) * 16;
    const unsigned short* src = Vp + (size_t)(kt * 64 + row) * 64 + cc;
    *(uint4*)&tile[row * 72 + cc] = *(const uint4*)src;
    *(uint4*)&tile[row * 72 + cc + 8] = *(const uint4*)(src + 8);
    __syncthreads();
    unsigned v[8];
    #pragma unroll
    for (int j = 0; j < 8; ++j) {
        unsigned short a = tile[(cc + 2 * j) * 72 + row];
        unsigned short bsh = tile[(cc + 2 * j + 1) * 72 + row];
        v[j] = (unsigned)a | ((unsigned)bsh << 16);
    }
    unsigned short* dst = vt + ((size_t)bh * 64 + row) * 2048 + kt * 64 + cc;
    *(uint4*)dst = make_uint4(v[0], v[1], v[2], v[3]);
    *(uint4*)(dst + 8) = make_uint4(v[4], v[5], v[6], v[7]);
}

// ------- MFMA flash attention: block = (b,h, 128-q); 4 waves x 32 q -------
// (round-4 best-measured variant, 94.3 us) Reg-resident P (swapped QK^T -> x16 PV).
// Double-buffered K/V LDS in T14 order: prefetch EARLY (after barrier), ds_write
// LATE (after compute) into the other buffer -> 1 barrier/kt, no VGPR WAR window.
__global__ __launch_bounds__(256, 4) void attn_mfma(const unsigned short* __restrict__ qkv,
                                                    const unsigned short* __restrict__ vt,
                                                    unsigned short* __restrict__ aout) {
    __shared__ unsigned short Ks[2][64 * 72];  // [kk 64][d 64] pad 72
    __shared__ unsigned short Vs[2][64 * 72];  // [d 64][kk 64] pad 72
    int bid0 = blockIdx.x;
    int bid = (bid0 & 7) * 128 + (bid0 >> 3);  // XCD swizzle, nwg=1024 (%8==0 -> bijective)
    int qt = bid & 15, h = (bid >> 4) & 15, b = bid >> 8;
    int t = threadIdx.x;
    int wave = t >> 6, lane = t & 63, lm = lane & 15, quad = lane >> 4;
    const unsigned short* Qb = qkv + (size_t)b * 6291456 + (size_t)h * 131072;
    const unsigned short* Kb = Qb + 2097152;
    const unsigned short* Vtb = vt + (size_t)(b * 16 + h) * 131072;  // [64][2048]
    int q0 = qt * 128 + wave * 32;

    // persistent Q fragments, pre-scaled by 0.125 * log2(e) (folds softmax scale + exp2 base)
    const float qs = 0.125f * LOG2E;
    short8 qf[2][2];
    #pragma unroll
    for (int i = 0; i < 2; ++i)
        #pragma unroll
        for (int c = 0; c < 2; ++c) {
            uint4 u = *(const uint4*)(Qb + (size_t)(q0 + i * 16 + lm) * 64 + c * 32 + quad * 8);
            float4 f0, f1; unpack8(u, f0, f1);
            uint4 v;
            v.x = pack2(f0.x * qs, f0.y * qs);
            v.y = pack2(f0.z * qs, f0.w * qs);
            v.z = pack2(f1.x * qs, f1.y * qs);
            v.w = pack2(f1.z * qs, f1.w * qs);
            qf[i][c] = *(short8*)&v;
        }

    short4v ones4;
    #pragma unroll
    for (int z = 0; z < 4; ++z) ones4[z] = (short)0x3F80;  // bf16 1.0

    f32x4 o[2][4] = {};
    f32x4 l_acc[2] = {};

    int srow = t >> 2, scol = (t & 3) * 16;

    // prologue: load tile 0 and stage it into buf0
    uint4 k0r, k1r, v0r, v1r;
    {
        const unsigned short* kp = Kb + (size_t)srow * 64 + scol;
        k0r = *(const uint4*)kp;
        k1r = *(const uint4*)(kp + 8);
        const unsigned short* vp = Vtb + (size_t)srow * 2048 + scol;
        v0r = *(const uint4*)vp;
        v1r = *(const uint4*)(vp + 8);
        *(uint4*)&Ks[0][srow * 72 + scol] = k0r;
        *(uint4*)&Ks[0][srow * 72 + scol + 8] = k1r;
        *(uint4*)&Vs[0][srow * 72 + scol] = v0r;
        *(uint4*)&Vs[0][srow * 72 + scol + 8] = v1r;
    }

    #pragma unroll 1
    for (int kt = 0; kt < 32; ++kt) {
        __syncthreads();   // buf[kt&1] (staged at end of prev iter / prologue) visible

        // issue next tile's global loads now; they land during this tile's compute
        if (kt < 31) {
            const unsigned short* kp = Kb + (size_t)((kt + 1) * 64 + srow) * 64 + scol;
            k0r = *(const uint4*)kp;
            k1r = *(const uint4*)(kp + 8);
            const unsigned short* vp = Vtb + (size_t)srow * 2048 + (kt + 1) * 64 + scol;
            v0r = *(const uint4*)vp;
            v1r = *(const uint4*)(vp + 8);
        }

        const unsigned short* ks = Ks[kt & 1];
        const unsigned short* vs = Vs[kt & 1];
        __builtin_amdgcn_s_setprio(1);

        // S^T = K Q^T per 16x16 tile: mfma(kf, qf) -> D[row=k-local][col=q-local].
        // Lane (lm,quad) holds P[q=i*16+lm][k=j*16+quad*4+0..3] == A-fragment of the
        // K=16 MFMA -> exp2+pack to short4 in registers, feed PV directly.
        short4v pf[2][4];
        #pragma unroll
        for (int j = 0; j < 4; ++j) {
            short8 kf0 = *(const short8*)&ks[(j * 16 + lm) * 72 + quad * 8];
            short8 kf1 = *(const short8*)&ks[(j * 16 + lm) * 72 + 32 + quad * 8];
            #pragma unroll
            for (int i = 0; i < 2; ++i) {
                f32x4 sf = {0.f, 0.f, 0.f, 0.f};
                sf = __builtin_amdgcn_mfma_f32_16x16x32_bf16(kf0, qf[i][0], sf, 0, 0, 0);
                sf = __builtin_amdgcn_mfma_f32_16x16x32_bf16(kf1, qf[i][1], sf, 0, 0, 0);
                uint2 u;
                u.x = pack2t(fexp2(sf[0]), fexp2(sf[1]));
                u.y = pack2t(fexp2(sf[2]), fexp2(sf[3]));
                pf[i][j] = *(short4v*)&u;
            }
        }

        // O += P V (K=16 MFMA, P from regs; V fragment = ds_read_b64 from Vt layout)
        #pragma unroll
        for (int jd = 0; jd < 4; ++jd)
            #pragma unroll
            for (int j = 0; j < 4; ++j) {
                short4v vf = *(const short4v*)&vs[(jd * 16 + lm) * 72 + j * 16 + quad * 4];
                o[0][jd] = mfma16(pf[0][j], vf, o[0][jd]);
                o[1][jd] = mfma16(pf[1][j], vf, o[1][jd]);
            }
        // l += P * ones (row-sums on MFMA pipe, same D layout as o)
        #pragma unroll
        for (int j = 0; j < 4; ++j) {
            l_acc[0] = mfma16(pf[0][j], ones4, l_acc[0]);
            l_acc[1] = mfma16(pf[1][j], ones4, l_acc[1]);
        }
        __builtin_amdgcn_s_setprio(0);

        // write-late: stage tile kt+1 into the other buffer. Safe with 1 barrier/kt:
        // any wave's reads of buf[(kt+1)&1] (its compute at kt-1) completed before it
        // arrived at barrier(kt), which this wave has passed.
        if (kt < 31) {
            unsigned short* kd = Ks[(kt + 1) & 1];
            unsigned short* vd = Vs[(kt + 1) & 1];
            *(uint4*)&kd[srow * 72 + scol] = k0r;
            *(uint4*)&kd[srow * 72 + scol + 8] = k1r;
            *(uint4*)&vd[srow * 72 + scol] = v0r;
            *(uint4*)&vd[srow * 72 + scol + 8] = v1r;
        }
    }
    // epilogue: aout[b*2048 + q][h*64 + d] bf16
    #pragma unroll
    for (int i = 0; i < 2; ++i)
        #pragma unroll
        for (int r = 0; r < 4; ++r) {
            float inv = 1.f / l_acc[i][r];
            int q = q0 + i * 16 + quad * 4 + r;
            size_t rowbase = ((size_t)b * 2048 + q) * 1024 + h * 64;
            #pragma unroll
            for (int jd = 0; jd < 4; ++jd)
                aout[rowbase + jd * 16 + lm] = f2bfbits(o[i][jd][r] * inv);
        }
}

extern "C" void kernel_launch(void* const* d_in, const int* in_sizes, int n_in,
                              void* d_out, int out_size, void* d_ws, size_t ws_size,
                              hipStream_t stream) {
    const float* xin  = (const float*)d_in[0];   // [8192,1024] fp32
    const float* wqkv = (const float*)d_in[1];   // [1024,3072] fp32
    const float* wo   = (const float*)d_in[2];   // [1024,1024] fp32
    float* out = (float*)d_out;                  // [8192,1024] fp32

    char* ws = (char*)d_ws;
    unsigned short* qkv   = (unsigned short*)(ws);                 // 50,331,648 B
    unsigned short* attn  = (unsigned short*)(ws + 50331648);      // 16,777,216 B
    unsigned short* wqkvT = (unsigned short*)(ws + 67108864);      //  6,291,456 B
    unsigned short* woT   = (unsigned short*)(ws + 73400320);      //  2,097,152 B
    unsigned short* vt    = (unsigned short*)(ws + 75497472);      // 16,777,216 B
    unsigned short* xb    = (unsigned short*)(ws + 92274688);      // 16,777,216 B

    dim3 blk(256);
    xbf_k<<<dim3(8192), blk, 0, stream>>>(xin, xb);
    t32cvt_k<<<dim3(3072 / 32, 1024 / 32), blk, 0, stream>>>(wqkv, wqkvT, 1024, 3072);
    t32cvt_k<<<dim3(1024 / 32, 1024 / 32), blk, 0, stream>>>(wo, woT, 1024, 1024);
    gemm_k<false><<<dim3(3072 / 128, 8192 / 128), blk, 0, stream>>>(xb, wqkvT, qkv, 8192, 3072, 1024);
    vt_k<<<dim3(32, 64), blk, 0, stream>>>(qkv, vt);
    attn_mfma<<<dim3(1024), blk, 0, stream>>>(qkv, vt, attn);
    gemm_k<true><<<dim3(1024 / 128, 8192 / 128), blk, 0, stream>>>(attn, woT, out, 8192, 1024, 1024);
}